// Round 3
// baseline (696.353 us; speedup 1.0000x reference)
//
#include <hip/hip_runtime.h>
#include <math.h>

#define NTOT 8192
#define DDIM 64
#define DOUTD 32
#define KDEG 16         // Chebyshev degree; |r|<=0.5 -> trunc err ~5e-5

// ws layout (float offsets), NS/JS chosen at runtime (16 if ws fits, else 8):
//  gF @ 0 (4096) | r @ 4096 (8192) | s @ 12288 (8192) | Yp @ 20480 (NS*64*8192)
//  P @ 20480+NS*YPSL (8192*32) | Dp @ +262144 (JS*8192*32)
#define WS_GF 0
#define WS_R 4096
#define WS_S 12288
#define WS_YP 20480
#define YPSL (DDIM * NTOT)   // 524288
#define DPSL (NTOT * DOUTD)  // 262144

// ---------------- gF = F^T F / (||F^T F||_F + 1e-6) ----------------
__global__ __launch_bounds__(256) void k_prep_gF(const float* __restrict__ F,
                                                 float* __restrict__ gF) {
    __shared__ __align__(16) float Fl[64][68];
    __shared__ float red[256];
    int tid = threadIdx.x;
    for (int l = tid; l < 64 * 16; l += 256) {
        int d = l >> 4, c = (l & 15) << 2;
        *(float4*)&Fl[d][c] = *(const float4*)(F + d * 64 + c);
    }
    __syncthreads();
    int pa = tid >> 4, pb = tid & 15;
    int a0 = pa * 4, b0 = pb * 4;
    float acc[4][4] = {};
#pragma unroll 8
    for (int d = 0; d < 64; ++d) {
        float4 av = *(float4*)&Fl[d][a0];
        float4 bv = *(float4*)&Fl[d][b0];
        float aa[4] = {av.x, av.y, av.z, av.w};
        float bb[4] = {bv.x, bv.y, bv.z, bv.w};
#pragma unroll
        for (int i = 0; i < 4; ++i)
#pragma unroll
            for (int j = 0; j < 4; ++j) acc[i][j] += aa[i] * bb[j];
    }
    float ss = 0.f;
#pragma unroll
    for (int i = 0; i < 4; ++i)
#pragma unroll
        for (int j = 0; j < 4; ++j) ss += acc[i][j] * acc[i][j];
    red[tid] = ss;
    __syncthreads();
    for (int off = 128; off > 0; off >>= 1) {
        if (tid < off) red[tid] += red[tid + off];
        __syncthreads();
    }
    float scale = 1.f / (sqrtf(red[0]) + 1e-6f);
#pragma unroll
    for (int i = 0; i < 4; ++i)
#pragma unroll
        for (int j = 0; j < 4; ++j)
            gF[(a0 + i) * 64 + (b0 + j)] = acc[i][j] * scale;
}

// ---------------- per-column Chebyshev params ----------------
__global__ __launch_bounds__(256) void k_prep_cols(const float* __restrict__ Lam,
                                                   const float* __restrict__ gammap,
                                                   float* __restrict__ r_arr,
                                                   float* __restrict__ s_arr) {
    int j = blockIdx.x * 256 + threadIdx.x;
    if (j < NTOT) {
        float a = gammap[0] * Lam[j];
        float q = sqrtf(fmaxf(1.f - a * a, 1e-12f));
        r_arr[j] = a / (1.f + q);
        s_arr[j] = 1.f / q;
    }
}

// ---------------- stage B: Yp[ns] = partial of Y = x^T Q_S  [64 x 8192] ----------------
// grid (32 jblocks of 256 cols, NS n-splits). block 256 = 4 igroups(16 rows) x 64 jlanes(4 cols).
// Q read DIRECT from global (float4, coalesced; intra-block 4x redundancy hits L1).
// x fragments are wave-uniform LDS broadcasts (ig uniform per wave).
__global__ __launch_bounds__(256) void k_gemmB(const float* __restrict__ x,
                                               const float* __restrict__ Q,
                                               float* __restrict__ Yp) {
    __shared__ __align__(16) float xs[64][64];
    int tid = threadIdx.x;
    int jl = tid & 63;
    int ig = tid >> 6;          // wave-uniform
    int i0 = ig * 16;
    int j0 = blockIdx.x * 256;
    int jj = j0 + 4 * jl;
    int ns = blockIdx.y;
    int NS = gridDim.y;
    int nrange = NTOT / NS;
    int n0base = ns * nrange;
    int nchunks = nrange / 64;
    float acc[16][4] = {};
    for (int nc = 0; nc < nchunks; ++nc) {
        int n0 = n0base + nc * 64;
        __syncthreads();
        for (int l = tid; l < 64 * 16; l += 256) {
            int row = l >> 4, c = (l & 15) << 2;
            *(float4*)&xs[row][c] = *(const float4*)(x + (size_t)(n0 + row) * 64 + c);
        }
        __syncthreads();
#pragma unroll 2
        for (int nn = 0; nn < 64; ++nn) {
            float4 q = *(const float4*)(Q + (size_t)(n0 + nn) * NTOT + jj);
            float4 x0 = *(float4*)&xs[nn][i0];
            float4 x1 = *(float4*)&xs[nn][i0 + 4];
            float4 x2 = *(float4*)&xs[nn][i0 + 8];
            float4 x3 = *(float4*)&xs[nn][i0 + 12];
            float xv[16] = {x0.x, x0.y, x0.z, x0.w, x1.x, x1.y, x1.z, x1.w,
                            x2.x, x2.y, x2.z, x2.w, x3.x, x3.y, x3.z, x3.w};
            float qq[4] = {q.x, q.y, q.z, q.w};
#pragma unroll
            for (int i = 0; i < 16; ++i)
#pragma unroll
                for (int j = 0; j < 4; ++j) acc[i][j] += xv[i] * qq[j];
        }
    }
#pragma unroll
    for (int ii = 0; ii < 16; ++ii) {
        float4 v = make_float4(acc[ii][0], acc[ii][1], acc[ii][2], acc[ii][3]);
        *(float4*)&Yp[(size_t)ns * YPSL + (size_t)(i0 + ii) * NTOT + jj] = v;
    }
}

// ---------------- stage C: fused Chebyshev resolvent + B_w projection ----------------
// grid 512 blocks x 16 cols. block 256 = 16 ti(4 rows) x 16 jt(1 col).
__global__ __launch_bounds__(256) void k_cheb(const float* __restrict__ Yp,
                                              const float* __restrict__ gF,
                                              const float* __restrict__ r_arr,
                                              const float* __restrict__ s_arr,
                                              const float* __restrict__ Bw,
                                              float* __restrict__ P, int nslices) {
    __shared__ __align__(16) float gfl[64][68];
    __shared__ float tb[2][64][18];
    __shared__ float bwT[64][33];
    int j0 = blockIdx.x * 16;
    int tid = threadIdx.x;
    for (int l = tid; l < 64 * 16; l += 256) {
        int k = l >> 4, c = (l & 15) << 2;
        *(float4*)&gfl[k][c] = *(const float4*)(gF + k * 64 + c);
    }
    for (int l = tid; l < 32 * 16; l += 256) {  // Bw [32][64] -> bwT [64][33]
        int o = l >> 4, c = (l & 15) << 2;
        float4 v = *(const float4*)(Bw + o * 64 + c);
        bwT[c + 0][o] = v.x; bwT[c + 1][o] = v.y;
        bwT[c + 2][o] = v.z; bwT[c + 3][o] = v.w;
    }
    for (int l = tid; l < 64 * 16; l += 256) {  // T0 = sum of Yp slices
        int row = l >> 4, col = l & 15;
        size_t base = (size_t)row * NTOT + j0 + col;
        float v = 0.f;
        for (int p = 0; p < nslices; ++p) v += Yp[(size_t)p * YPSL + base];
        tb[0][row][col] = v;
    }
    __syncthreads();
    int ti = tid >> 4;   // i0 = 4*ti
    int jt = tid & 15;   // column
    int i0 = ti * 4;
    int jc = j0 + jt;
    float r = r_arr[jc], s = s_arr[jc];
    float rp = 1.f;
    float u[4];
#pragma unroll
    for (int ii = 0; ii < 4; ++ii) u[ii] = s * tb[0][i0 + ii][jt];
    int cur = 0, prv = 1;
    for (int m = 1; m <= KDEG; ++m) {
        float mv[4] = {};
#pragma unroll 8
        for (int k = 0; k < 64; ++k) {
            float4 g = *(float4*)&gfl[k][i0];  // gF symmetric
            float t = tb[cur][k][jt];
            mv[0] += g.x * t; mv[1] += g.y * t;
            mv[2] += g.z * t; mv[3] += g.w * t;
        }
        rp *= r;
        float cm = 2.f * s * rp;
#pragma unroll
        for (int ii = 0; ii < 4; ++ii) {
            float tm = (m == 1) ? mv[ii] : 2.f * mv[ii] - tb[prv][i0 + ii][jt];
            tb[prv][i0 + ii][jt] = tm;
            u[ii] += cm * tm;
        }
        int tmp = cur; cur = prv; prv = tmp;
        __syncthreads();
    }
#pragma unroll
    for (int ii = 0; ii < 4; ++ii) tb[0][i0 + ii][jt] = u[ii];
    __syncthreads();
    // P[j][o] = sum_i Bw[o][i] u[i][j] ; thread: o = tid&31, cols {tid>>5, 8+(tid>>5)}
    int o = tid & 31;
    int c0 = tid >> 5;
    float p0 = 0.f, p1 = 0.f;
#pragma unroll 8
    for (int i = 0; i < 64; ++i) {
        float b = bwT[i][o];
        p0 += b * tb[0][i][c0];
        p1 += b * tb[0][i][c0 + 8];
    }
    P[(size_t)(j0 + c0) * DOUTD + o] = p0;
    P[(size_t)(j0 + c0 + 8) * DOUTD + o] = p1;
}

// ---------------- stage D: Dp[js] = partial of out = Q_S @ P  [8192 x 32] ----------------
// grid (64 iblocks of 128 rows, JS j-splits). block 256 = 32 ti(4 contig rows) x 8 to(4 o).
__global__ __launch_bounds__(256) void k_gemmD(const float* __restrict__ Q,
                                               const float* __restrict__ P,
                                               float* __restrict__ Dp) {
    __shared__ __align__(16) float qs[128][68];
    __shared__ __align__(16) float ps[64][36];
    int i0b = blockIdx.x * 128;
    int js = blockIdx.y;
    int JS = gridDim.y;
    int jrange = NTOT / JS;
    int j0s = js * jrange;
    int tid = threadIdx.x;
    int ti = tid & 31;   // rows 4*ti .. 4*ti+3
    int to = tid >> 5;   // o = 4*to .. +3
    float acc[4][4] = {};
    for (int jt = 0; jt < jrange / 64; ++jt) {
        int j0 = j0s + jt * 64;
        __syncthreads();
        for (int l = tid; l < 128 * 16; l += 256) {
            int rr = l >> 4, c = (l & 15) << 2;
            *(float4*)&qs[rr][c] = *(const float4*)(Q + (size_t)(i0b + rr) * NTOT + j0 + c);
        }
        for (int l = tid; l < 64 * 8; l += 256) {
            int rr = l >> 3, c = (l & 7) << 2;
            *(float4*)&ps[rr][c] = *(const float4*)(P + (size_t)(j0 + rr) * DOUTD + c);
        }
        __syncthreads();
#pragma unroll 4
        for (int jj = 0; jj < 64; jj += 4) {
            float4 p0 = *(float4*)&ps[jj + 0][to * 4];
            float4 p1 = *(float4*)&ps[jj + 1][to * 4];
            float4 p2 = *(float4*)&ps[jj + 2][to * 4];
            float4 p3 = *(float4*)&ps[jj + 3][to * 4];
#pragma unroll
            for (int rr = 0; rr < 4; ++rr) {
                float4 q = *(float4*)&qs[ti * 4 + rr][jj];
                acc[rr][0] += q.x * p0.x + q.y * p1.x + q.z * p2.x + q.w * p3.x;
                acc[rr][1] += q.x * p0.y + q.y * p1.y + q.z * p2.y + q.w * p3.y;
                acc[rr][2] += q.x * p0.z + q.y * p1.z + q.z * p2.z + q.w * p3.z;
                acc[rr][3] += q.x * p0.w + q.y * p1.w + q.z * p2.w + q.w * p3.w;
            }
        }
    }
#pragma unroll
    for (int rr = 0; rr < 4; ++rr) {
        float4 v = make_float4(acc[rr][0], acc[rr][1], acc[rr][2], acc[rr][3]);
        *(float4*)&Dp[(size_t)js * DPSL + (size_t)(i0b + ti * 4 + rr) * DOUTD + to * 4] = v;
    }
}

// ---------------- reduce JS partial outputs ----------------
__global__ __launch_bounds__(256) void k_reduce_out(const float* __restrict__ Dp,
                                                    float* __restrict__ out, int js) {
    int idx = (blockIdx.x * 256 + threadIdx.x) * 4;
    float4 s = *(const float4*)(Dp + idx);
    for (int p = 1; p < js; ++p) {
        float4 v = *(const float4*)(Dp + (size_t)p * DPSL + idx);
        s.x += v.x; s.y += v.y; s.z += v.z; s.w += v.w;
    }
    *(float4*)(out + idx) = s;
}

extern "C" void kernel_launch(void* const* d_in, const int* in_sizes, int n_in,
                              void* d_out, int out_size, void* d_ws, size_t ws_size,
                              hipStream_t stream) {
    const float* x = (const float*)d_in[0];
    const float* Q = (const float*)d_in[1];
    const float* Lam = (const float*)d_in[2];
    const float* F = (const float*)d_in[3];
    const float* Bw = (const float*)d_in[4];
    const float* gamma = (const float*)d_in[5];

    // runtime split selection by ws capacity
    int NS = 16, JS = 16;
    size_t need16 = (size_t)(WS_YP + 16 * YPSL + NTOT * DOUTD + 16 * DPSL) * 4;
    if (ws_size < need16) { NS = 8; JS = 8; }

    float* ws = (float*)d_ws;
    float* gF = ws + WS_GF;
    float* r_arr = ws + WS_R;
    float* s_arr = ws + WS_S;
    float* Yp = ws + WS_YP;
    float* P = Yp + (size_t)NS * YPSL;
    float* Dp = P + (size_t)NTOT * DOUTD;
    float* out = (float*)d_out;

    k_prep_gF<<<1, 256, 0, stream>>>(F, gF);
    k_prep_cols<<<32, 256, 0, stream>>>(Lam, gamma, r_arr, s_arr);
    k_gemmB<<<dim3(NTOT / 256, NS), 256, 0, stream>>>(x, Q, Yp);
    k_cheb<<<NTOT / 16, 256, 0, stream>>>(Yp, gF, r_arr, s_arr, Bw, P, NS);
    k_gemmD<<<dim3(NTOT / 128, JS), 256, 0, stream>>>(Q, P, Dp);
    k_reduce_out<<<NTOT * DOUTD / 4 / 256, 256, 0, stream>>>(Dp, out, JS);
}